// Round 3
// baseline (178.417 us; speedup 1.0000x reference)
//
#include <hip/hip_runtime.h>
#include <math.h>

// GptOssTopKRouter on MI355X.
// X[16384,2880] fp32 @ W[32,2880]^T + b -> top4 -> softmax -> scatter.
// HBM-bound on X (189 MB, floor ~30 us). Structure:
//   - pre-kernel transposes W to WT[2880][32]; main kernel reads WT through
//     CONSTANT address space (addrspace(4)) at wave-uniform addresses ->
//     s_load_dwordx4/x8/x16 on the SMEM pipe, zero vector-memory cost.
//     (Round-2 lesson: generic-AS uniform loads stayed vector loads -> 23k
//      vmem instr/CU through TCP was the bottleneck.)
//   - 1 block = 64 tokens = lane index; 8 waves split hidden dim.
//     X streamed in 96-float chunks: coalesced global->reg->LDS (XOR-swizzled),
//     double-buffered, raw s_barrier + manual lgkmcnt (no vmcnt(0) drain).

#define HIDDEN 2880
#define NE 32
#define TOPK 4
#define TPB 64          // tokens per block (= lanes)
#define KC 96           // hidden floats per chunk per token
#define NCH 30          // 2880 / 96
#define SLOTS 24        // float4 slots per row-chunk (96/4)
#define SPW 3           // staging float4s per wave per chunk (24*64/64/8)
#define MPW 12          // hidden floats per wave per chunk (96/8)

#define CONSTANT_AS __attribute__((address_space(4)))

__global__ void transpose_w_kernel(const float* __restrict__ w, float* __restrict__ wt) {
    int i = blockIdx.x * 256 + threadIdx.x;
    if (i < NE * HIDDEN) {
        int e = i / HIDDEN;
        int h = i - e * HIDDEN;
        wt[h * NE + e] = w[i];
    }
}

__global__ __launch_bounds__(512, 2)
void router_kernel(const float* __restrict__ x,
                   const float* __restrict__ wt,
                   const float* __restrict__ bias,
                   float* __restrict__ out_scores,
                   float* __restrict__ out_idx)
{
    __shared__ float sm[2 * TPB * KC];          // 2 x 24 KB, reused by epilogue
    float* buf0 = sm;
    float* buf1 = sm + TPB * KC;

    const int tid  = threadIdx.x;
    const int lane = tid & 63;
    const int ws   = __builtin_amdgcn_readfirstlane(tid >> 6);
    const int tok0 = blockIdx.x * TPB;
    const float* __restrict__ xblk = x + (size_t)tok0 * HIDDEN;

    // weights via CONSTANT address space: uniform address -> s_load (SMEM pipe)
    const CONSTANT_AS float* wc = (const CONSTANT_AS float*)wt;

    float acc[NE];
#pragma unroll
    for (int e = 0; e < NE; ++e) acc[e] = 0.0f;

    // staging geometry: flat float4 index F4 = (ws*SPW+q)*64 + lane over the
    // 64x24 float4 tile; row = token, slot = float4-in-row (linear on global side)
    int rowq[SPW], sltq[SPW];
    const float* xq[SPW];
#pragma unroll
    for (int q = 0; q < SPW; ++q) {
        int F4 = (ws * SPW + q) * 64 + lane;    // 0..1535
        rowq[q] = F4 / SLOTS;
        sltq[q] = F4 - rowq[q] * SLOTS;
        xq[q]   = xblk + (size_t)rowq[q] * HIDDEN + sltq[q] * 4;
    }

    float4 ga[SPW], gb[SPW];

#define GLOAD(g, c) do { _Pragma("unroll")                                        \
    for (int q = 0; q < SPW; ++q)                                                 \
        g[q] = *reinterpret_cast<const float4*>(xq[q] + (c) * KC);                \
} while (0)

    // XOR-swizzle the destination slot (low 3 bits ^ row) -> conflict-light
    // column-slice ds_read later (2-way residual = free per m136).
#define SWRITE(dst, g) do { _Pragma("unroll")                                     \
    for (int q = 0; q < SPW; ++q) {                                               \
        int jj = (sltq[q] & ~7) | ((sltq[q] ^ rowq[q]) & 7);                      \
        *reinterpret_cast<float4*>((dst) + rowq[q] * KC + jj * 4) = g[q];         \
    }                                                                             \
} while (0)

#define COMPUTE(src, c) do {                                                      \
    float xf[MPW];                                                                \
    _Pragma("unroll")                                                             \
    for (int i = 0; i < SPW; ++i) {                                               \
        int k = ws * SPW + i;                                                     \
        int jj = (k & ~7) | ((k ^ lane) & 7);                                     \
        float4 v = *reinterpret_cast<const float4*>((src) + lane * KC + jj * 4);  \
        xf[i*4+0] = v.x; xf[i*4+1] = v.y; xf[i*4+2] = v.z; xf[i*4+3] = v.w;       \
    }                                                                             \
    const CONSTANT_AS float* wrow = wc + ((size_t)(c) * KC + ws * MPW) * NE;      \
    _Pragma("unroll")                                                             \
    for (int m = 0; m < MPW; ++m) {                                               \
        _Pragma("unroll")                                                         \
        for (int e = 0; e < NE; ++e)                                              \
            acc[e] = fmaf(wrow[m * NE + e], xf[m], acc[e]);                       \
    }                                                                             \
} while (0)

    // raw barrier: do NOT use __syncthreads() in the main loop (it drains
    // vmcnt(0) and kills the global prefetch). ds_writes drained manually.
#define LGKM0_BARRIER() do {                                                      \
    asm volatile("s_waitcnt lgkmcnt(0)" ::: "memory");                            \
    __builtin_amdgcn_s_barrier();                                                 \
} while (0)

    GLOAD(ga, 0);
#pragma unroll 1
    for (int cc = 0; cc < NCH / 2; ++cc) {
        const int c0 = 2 * cc;
        GLOAD(gb, c0 + 1);
        SWRITE(buf0, ga);
        LGKM0_BARRIER();
        COMPUTE(buf0, c0);
        if (c0 + 2 < NCH) GLOAD(ga, c0 + 2);
        SWRITE(buf1, gb);
        LGKM0_BARRIER();
        COMPUTE(buf1, c0 + 1);
    }

#undef GLOAD
#undef SWRITE
#undef COMPUTE
#undef LGKM0_BARRIER

    // ---- epilogue: cross-wave reduction (reuses sm; all lgkm drained) ----
    float* part   = sm;                       // [4][TPB][NE+1]
    float* logits = sm + 4 * TPB * (NE + 1);  // [TPB][NE+1]

    __syncthreads();
    if (ws >= 4) {
#pragma unroll
        for (int e = 0; e < NE; ++e) part[((ws - 4) * TPB + lane) * (NE + 1) + e] = acc[e];
    }
    __syncthreads();
    if (ws < 4) {
#pragma unroll
        for (int e = 0; e < NE; ++e) part[(ws * TPB + lane) * (NE + 1) + e] += acc[e];
    }
    __syncthreads();

    for (int i2 = tid; i2 < TPB * NE; i2 += 512) {
        const int t2 = i2 >> 5, e2 = i2 & 31;
        float s = bias[e2];
#pragma unroll
        for (int p = 0; p < 4; ++p) s += part[(p * TPB + t2) * (NE + 1) + e2];
        logits[t2 * (NE + 1) + e2] = s;
    }
    __syncthreads();

    // ---- top-4 + softmax + scatter, one lane per token (wave 0) ----
    if (tid < TPB) {
        float vals[TOPK];
        int   idxs[TOPK];
        unsigned chosen = 0u;
#pragma unroll
        for (int k = 0; k < TOPK; ++k) {
            float m = -INFINITY; int mi = 0;
            for (int e = 0; e < NE; ++e) {
                const float v = logits[tid * (NE + 1) + e];
                const bool take = (((chosen >> e) & 1u) == 0u) && (v > m);
                m  = take ? v : m;
                mi = take ? e : mi;
            }
            vals[k] = m; idxs[k] = mi; chosen |= (1u << (unsigned)mi);
        }
        const float mx = vals[0];
        float p[TOPK]; float sum = 0.0f;
#pragma unroll
        for (int k = 0; k < TOPK; ++k) { p[k] = expf(vals[k] - mx); sum += p[k]; }
        const float inv = 1.0f / sum;

        const int t = tok0 + tid;
        float* srow = out_scores + (size_t)t * NE;
#pragma unroll
        for (int e = 0; e < NE; ++e) {
            float v = 0.0f;
#pragma unroll
            for (int k = 0; k < TOPK; ++k) v = (e == idxs[k]) ? p[k] * inv : v;
            srow[e] = v;
        }
#pragma unroll
        for (int k = 0; k < TOPK; ++k)
            out_idx[(size_t)t * TOPK + k] = (float)idxs[k];
    }
}

extern "C" void kernel_launch(void* const* d_in, const int* in_sizes, int n_in,
                              void* d_out, int out_size, void* d_ws, size_t ws_size,
                              hipStream_t stream)
{
    const float* x = (const float*)d_in[0];
    const float* w = (const float*)d_in[1];
    const float* b = (const float*)d_in[2];
    const int T = in_sizes[0] / HIDDEN;            // 16384 tokens

    float* wt = (float*)d_ws;                      // [2880][32] = 368.6 KB scratch
    float* out        = (float*)d_out;
    float* out_scores = out;                       // [T, 32]
    float* out_idx    = out + (size_t)T * NE;      // [T, 4] as fp32 values

    transpose_w_kernel<<<dim3((NE * HIDDEN + 255) / 256), dim3(256), 0, stream>>>(w, wt);
    router_kernel<<<dim3(T / TPB), dim3(512), 0, stream>>>(x, wt, b, out_scores, out_idx);
}

// Round 4
// 64.051 us; speedup vs baseline: 2.7856x; 2.7856x over previous
//
#include <hip/hip_runtime.h>
#include <math.h>

// GptOssTopKRouter on MI355X — round 4.
// X[16384,2880] fp32 @ W[32,2880]^T + b -> top4 -> softmax -> scatter.
//
// Round-3 lesson: with lane=token, weights are wave-uniform -> every weight
// instruction moves only 4 useful floats (23k vmem instr/CU, latency-bound,
// 190 us). Flip the mapping: lane = (expert-quad, h-position) so WEIGHTS are
// the lane-private coalesced operand (1 dwordx4 = 256 weight floats/wave),
// and X is transposed through a small per-wave private LDS tile (no barriers
// in the main loop; waves fully independent).
//
// wave  = (token-group tg in 0..3 [16 tokens], h-half in 0..1 [1440 h])
// lane  = (e4 in 0..7 [4 experts], h8 in 0..7 [h position])
// chunk = 32 h: stage 16t x 32h -> XT[32][20] (pad-> conflict-free b128),
//         4 steps of {1 weight dwordx4, 4 X ds_read_b128, 64 fmaf}.
// acc   = float4 acc[16] (token x expert-quad) = 64 VGPR, static indexing.

#define HIDDEN 2880
#define NE 32
#define TOPK 4
#define TPB 64            // tokens per block
#define TPW 16            // tokens per wave
#define HHALF 1440        // h per half
#define CH 32             // h per chunk
#define NCH 45            // chunks per half (1440/32)
#define ROWP 20           // padded LDS row: 16 t + 4 pad (80 B, 16B-aligned)
#define PSTRIDE 36        // part row stride (144 B, 16B-aligned)

__global__ void transpose_w_kernel(const float* __restrict__ w, float* __restrict__ wt) {
    int i = blockIdx.x * 256 + threadIdx.x;
    if (i < NE * HIDDEN) {
        int e = i / HIDDEN;
        int h = i - e * HIDDEN;
        wt[h * NE + e] = w[i];
    }
}

#define FMA4(a, xs, w4) do {                         \
    (a).x = fmaf((xs), (w4).x, (a).x);               \
    (a).y = fmaf((xs), (w4).y, (a).y);               \
    (a).z = fmaf((xs), (w4).z, (a).z);               \
    (a).w = fmaf((xs), (w4).w, (a).w); } while (0)

__global__ __launch_bounds__(512, 2)
void router_kernel(const float* __restrict__ x,
                   const float* __restrict__ wt,
                   const float* __restrict__ bias,
                   float* __restrict__ out_scores,
                   float* __restrict__ out_idx)
{
    __shared__ float xt[8 * 2 * CH * ROWP];          // 40960 B: per-wave double-buffered XT
    __shared__ float part[2][4][TPW][PSTRIDE];       // 18432 B: h-half partials (+score stash)

    const int tid  = threadIdx.x;
    const int lane = tid & 63;
    const int w    = tid >> 6;
    const int tg   = w & 3;           // token group
    const int half = w >> 2;          // h half
    const int e4   = lane & 7;        // expert quad
    const int h8   = lane >> 3;       // h position within 8
    const int tok0 = blockIdx.x * TPB + tg * TPW;

    // staging: lane reads x[tok0+srow][hbase + scol .. +3] (8 rows/instr, coalesced)
    const int srow = lane >> 3;
    const int scol = (lane & 7) * 4;
    const float* xp0 = x + (size_t)(tok0 + srow) * HIDDEN + half * HHALF + scol;
    const float* xp1 = xp0 + (size_t)8 * HIDDEN;
    const float* wp  = wt + (half * HHALF + h8) * NE + e4 * 4;

    float* xtw = xt + w * (2 * CH * ROWP);           // private per-wave region

    float4 acc[16];
#pragma unroll
    for (int i = 0; i < 16; ++i) acc[i] = make_float4(0.f, 0.f, 0.f, 0.f);

#define STAGE(buf, a0, a1) do {                                                   \
    (buf)[(scol + 0) * ROWP + srow] = (a0).x;                                     \
    (buf)[(scol + 1) * ROWP + srow] = (a0).y;                                     \
    (buf)[(scol + 2) * ROWP + srow] = (a0).z;                                     \
    (buf)[(scol + 3) * ROWP + srow] = (a0).w;                                     \
    (buf)[(scol + 0) * ROWP + 8 + srow] = (a1).x;                                 \
    (buf)[(scol + 1) * ROWP + 8 + srow] = (a1).y;                                 \
    (buf)[(scol + 2) * ROWP + 8 + srow] = (a1).z;                                 \
    (buf)[(scol + 3) * ROWP + 8 + srow] = (a1).w; } while (0)

#define COMPUTE(buf, c) do {                                                      \
    _Pragma("unroll")                                                             \
    for (int s = 0; s < 4; ++s) {                                                 \
        const float4 w4 = *(const float4*)(wp + ((c) * CH + s * 8) * NE);         \
        _Pragma("unroll")                                                         \
        for (int tq = 0; tq < 4; ++tq) {                                          \
            const float4 xv = *(const float4*)((buf) + (s * 8 + h8) * ROWP + tq * 4); \
            FMA4(acc[tq * 4 + 0], xv.x, w4);                                      \
            FMA4(acc[tq * 4 + 1], xv.y, w4);                                      \
            FMA4(acc[tq * 4 + 2], xv.z, w4);                                      \
            FMA4(acc[tq * 4 + 3], xv.w, w4);                                      \
        }                                                                         \
    } } while (0)

    float4 c0 = *(const float4*)(xp0);
    float4 c1 = *(const float4*)(xp1);

    for (int c = 0; c < NCH - 1; ++c) {
        const float4 n0 = *(const float4*)(xp0 + (c + 1) * CH);
        const float4 n1 = *(const float4*)(xp1 + (c + 1) * CH);
        float* buf = xtw + (c & 1) * (CH * ROWP);
        STAGE(buf, c0, c1);
        COMPUTE(buf, c);
        c0 = n0; c1 = n1;
    }
    {
        float* buf = xtw + ((NCH - 1) & 1) * (CH * ROWP);
        STAGE(buf, c0, c1);
        COMPUTE(buf, NCH - 1);
    }

#undef STAGE
#undef COMPUTE
#undef FMA4

    // ---- reduce over the 8 h-positions (lane bits 3..5) ----
#pragma unroll
    for (int i = 0; i < 16; ++i) {
#pragma unroll
        for (int m = 8; m <= 32; m <<= 1) {
            acc[i].x += __shfl_xor(acc[i].x, m);
            acc[i].y += __shfl_xor(acc[i].y, m);
            acc[i].z += __shfl_xor(acc[i].z, m);
            acc[i].w += __shfl_xor(acc[i].w, m);
        }
    }

    // lanes 0..7 (one per expert-quad) write the wave's 16 tokens
    if (h8 == 0) {
#pragma unroll
        for (int t = 0; t < TPW; ++t)
            *reinterpret_cast<float4*>(&part[half][tg][t][e4 * 4]) = acc[t];
    }
    __syncthreads();

    // ---- top-4 + softmax, one lane per token (wave 0) ----
    float* scorebuf = &part[0][0][0][0];             // reused after logits read
    if (tid < TPB) {
        const int ttg = tid >> 4, tt = tid & 15;
        float lg[NE];
#pragma unroll
        for (int e = 0; e < NE; ++e)
            lg[e] = part[0][ttg][tt][e] + part[1][ttg][tt][e] + bias[e];

        float vals[TOPK]; int idxs[TOPK]; unsigned chosen = 0u;
#pragma unroll
        for (int k = 0; k < TOPK; ++k) {
            float m = -INFINITY; int mi = 0;
#pragma unroll
            for (int e = 0; e < NE; ++e) {
                const bool take = (((chosen >> e) & 1u) == 0u) && (lg[e] > m);
                m  = take ? lg[e] : m;
                mi = take ? e : mi;
            }
            vals[k] = m; idxs[k] = mi; chosen |= (1u << (unsigned)mi);
        }
        const float mx = vals[0];
        float p[TOPK]; float sum = 0.f;
#pragma unroll
        for (int k = 0; k < TOPK; ++k) { p[k] = __expf(vals[k] - mx); sum += p[k]; }
        const float inv = 1.0f / sum;
#pragma unroll
        for (int e = 0; e < NE; ++e) {
            float v = 0.f;
#pragma unroll
            for (int k = 0; k < TOPK; ++k) v = (e == idxs[k]) ? p[k] * inv : v;
            scorebuf[tid * 33 + e] = v;              // stride 33: conflict-free stash
        }
        const int t = blockIdx.x * TPB + tid;
        float4 iv = make_float4((float)idxs[0], (float)idxs[1], (float)idxs[2], (float)idxs[3]);
        *reinterpret_cast<float4*>(out_idx + (size_t)t * TOPK) = iv;   // coalesced
    }
    __syncthreads();

    // coalesced score store: 2048 floats, 512 threads x float4
    {
        const int f = tid * 4;
        const int t = f >> 5, e = f & 31;
        float4 v = make_float4(scorebuf[t * 33 + e], scorebuf[t * 33 + e + 1],
                               scorebuf[t * 33 + e + 2], scorebuf[t * 33 + e + 3]);
        *reinterpret_cast<float4*>(out_scores + (size_t)blockIdx.x * TPB * NE + f) = v;
    }
}

extern "C" void kernel_launch(void* const* d_in, const int* in_sizes, int n_in,
                              void* d_out, int out_size, void* d_ws, size_t ws_size,
                              hipStream_t stream)
{
    const float* x = (const float*)d_in[0];
    const float* w = (const float*)d_in[1];
    const float* b = (const float*)d_in[2];
    const int T = in_sizes[0] / HIDDEN;            // 16384 tokens

    float* wt = (float*)d_ws;                      // [2880][32] = 368.6 KB scratch
    float* out        = (float*)d_out;
    float* out_scores = out;                       // [T, 32]
    float* out_idx    = out + (size_t)T * NE;      // [T, 4] as fp32 values

    transpose_w_kernel<<<dim3((NE * HIDDEN + 255) / 256), dim3(256), 0, stream>>>(w, wt);
    router_kernel<<<dim3(T / TPB), dim3(512), 0, stream>>>(x, wt, b, out_scores, out_idx);
}

// Round 5
// 57.077 us; speedup vs baseline: 3.1259x; 1.1222x over previous
//
#include <hip/hip_runtime.h>
#include <math.h>

// GptOssTopKRouter on MI355X — round 5.
// X[16384,2880] fp32 @ W[32,2880]^T + b -> top4 -> softmax -> scatter.
//
// Round-4 post-mortem: LDS pipe was the wall (~96k cyc/CU: 8 conflicted
// scalar ds_write + 16 ds_read_b128 per 32h-chunk per wave). This round:
//   - 8 experts per lane (lane = eg x h16): each ds_read_b128 feeds 32 FMAs
//     (reads halve), weights still per-lane coalesced dwordx4 from WT.
//   - staging loads float2 spanning 2 LDS rows -> writes become 4 paired
//     (write2-mergeable) stores; XOR col-swizzle makes writes<=2-way and
//     reads exactly 2/bank (free).
//   - weights register-double-buffered one chunk ahead (hide L2 latency).
//   - epilogue reduce = halving butterfly (120 shuffles/wave, one-time).
// wave = (tg in 0..3 [16 tokens], half in 0..1 [1440 h]); chunk = 32 h.
// acc = float4 acc[32] (16 tokens x 8 experts) = 128 VGPR, static indexing.

#define HIDDEN 2880
#define NE 32
#define TOPK 4
#define TPB 64            // tokens per block
#define HHALF 1440        // h per half
#define CH 32             // h per chunk
#define NCH 45            // chunks per half
#define ROWP 20           // padded LDS row: 16 t + 4 pad (80 B)
#define TILE (CH * ROWP)  // 640 floats per buffer
#define PST 36            // part row stride

__global__ void transpose_w_kernel(const float* __restrict__ w, float* __restrict__ wt) {
    int i = blockIdx.x * 256 + threadIdx.x;
    if (i < NE * HIDDEN) {
        int e = i / HIDDEN;
        int h = i - e * HIDDEN;
        wt[h * NE + e] = w[i];
    }
}

#define FMA4(a, xs, w4) do {                         \
    (a).x = fmaf((xs), (w4).x, (a).x);               \
    (a).y = fmaf((xs), (w4).y, (a).y);               \
    (a).z = fmaf((xs), (w4).z, (a).z);               \
    (a).w = fmaf((xs), (w4).w, (a).w); } while (0)

__device__ __forceinline__ float4 selred(float4 lo, float4 hi, int sel, int mask) {
    float gx = sel ? lo.x : hi.x, kx = sel ? hi.x : lo.x;
    float gy = sel ? lo.y : hi.y, ky = sel ? hi.y : lo.y;
    float gz = sel ? lo.z : hi.z, kz = sel ? hi.z : lo.z;
    float gw = sel ? lo.w : hi.w, kw = sel ? hi.w : lo.w;
    return make_float4(kx + __shfl_xor(gx, mask), ky + __shfl_xor(gy, mask),
                       kz + __shfl_xor(gz, mask), kw + __shfl_xor(gw, mask));
}

__global__ __launch_bounds__(512, 2)
void router_kernel(const float* __restrict__ x,
                   const float* __restrict__ wt,
                   const float* __restrict__ bias,
                   float* __restrict__ out_scores,
                   float* __restrict__ out_idx)
{
    __shared__ float xt[8 * 2 * TILE];        // 40 KB: per-wave double-buffered XT
    __shared__ float part[2][TPB][PST];       // 18 KB: h-half partials

    const int tid  = threadIdx.x;
    const int lane = tid & 63;
    const int w    = tid >> 6;
    const int tg   = w & 3;           // token group (16 tokens)
    const int half = w >> 2;          // h half
    const int eg   = lane & 3;        // expert group (8 experts)
    const int h16  = lane >> 2;       // h position within 16
    const int r4   = lane >> 4;       // staging: token sub-index
    const int hp   = lane & 15;       // staging: h-pair index
    const int tok0 = blockIdx.x * TPB + tg * 16;

    // staging source: lane reads float2 x[tok0+4i+r4][hb + 2hp .. +1]
    const float* xs = x + (size_t)(tok0 + r4) * HIDDEN + half * HHALF + 2 * hp;
    // weights: lane's 8 experts at its h16 rows of WT
    const float* wp = wt + (size_t)(half * HHALF + h16) * NE + eg * 8;

    float* xtw = xt + w * (2 * TILE);
    float* buf0 = xtw;
    float* buf1 = xtw + TILE;

    float4 acc[32];
#pragma unroll
    for (int i = 0; i < 32; ++i) acc[i] = make_float4(0.f, 0.f, 0.f, 0.f);

    const int wsz = ((hp >> 2) & 3) << 2;     // write-side col swizzle

#define XLOAD(g, c) do { _Pragma("unroll")                                        \
    for (int i = 0; i < 4; ++i)                                                   \
        g[i] = *(const float2*)(xs + (size_t)i * 4 * HIDDEN + (size_t)(c) * CH);  \
} while (0)

#define WLOAD(wv, c) do { _Pragma("unroll")                                       \
    for (int s = 0; s < 2; ++s) {                                                 \
        wv[s][0] = *(const float4*)(wp + ((size_t)(c) * CH + s * 16) * NE);       \
        wv[s][1] = *(const float4*)(wp + ((size_t)(c) * CH + s * 16) * NE + 4);   \
    } } while (0)

#define STAGE(buf, g) do { _Pragma("unroll")                                      \
    for (int i = 0; i < 4; ++i) {                                                 \
        const int cs = (4 * i + r4) ^ wsz;                                        \
        (buf)[(2 * hp) * ROWP + cs]     = g[i].x;                                 \
        (buf)[(2 * hp + 1) * ROWP + cs] = g[i].y;                                 \
    } } while (0)

#define COMPUTE(buf, wv) do { _Pragma("unroll")                                   \
    for (int s = 0; s < 2; ++s) {                                                 \
        const int S = s * 16 + h16;                                               \
        const int q = (S >> 3) & 3;                                               \
        _Pragma("unroll")                                                         \
        for (int tq = 0; tq < 4; ++tq) {                                          \
            const float4 xv = *(const float4*)((buf) + S * ROWP + ((tq * 4) ^ (q << 2))); \
            FMA4(acc[(tq*4+0)*2+0], xv.x, wv[s][0]); FMA4(acc[(tq*4+0)*2+1], xv.x, wv[s][1]); \
            FMA4(acc[(tq*4+1)*2+0], xv.y, wv[s][0]); FMA4(acc[(tq*4+1)*2+1], xv.y, wv[s][1]); \
            FMA4(acc[(tq*4+2)*2+0], xv.z, wv[s][0]); FMA4(acc[(tq*4+2)*2+1], xv.z, wv[s][1]); \
            FMA4(acc[(tq*4+3)*2+0], xv.w, wv[s][0]); FMA4(acc[(tq*4+3)*2+1], xv.w, wv[s][1]); \
        } } } while (0)

    float2 xa[4], xb[4];
    float4 wa[2][2], wb[2][2];

    XLOAD(xa, 0); WLOAD(wa, 0);
#pragma unroll 1
    for (int cc = 0; cc < NCH / 2; ++cc) {    // 22 pairs + tail (NCH=45)
        const int c0 = 2 * cc;
        XLOAD(xb, c0 + 1); WLOAD(wb, c0 + 1);
        STAGE(buf0, xa); COMPUTE(buf0, wa);
        if (c0 + 2 < NCH) { XLOAD(xa, c0 + 2); WLOAD(wa, c0 + 2); }
        STAGE(buf1, xb); COMPUTE(buf1, wb);
    }
    STAGE(buf0, xa); COMPUTE(buf0, wa);       // tail chunk 44

#undef XLOAD
#undef WLOAD
#undef STAGE
#undef COMPUTE
#undef FMA4

    // ---- in-wave halving butterfly over h16 (lane bits 2..5) ----
    const int s1 = (lane >> 2) & 1, s2 = (lane >> 3) & 1;
    const int s3 = (lane >> 4) & 1, s4 = (lane >> 5) & 1;

    float4 na[16];
#pragma unroll
    for (int t = 0; t < 8; ++t)
#pragma unroll
        for (int p = 0; p < 2; ++p)
            na[t*2+p] = selred(acc[t*2+p], acc[(t+8)*2+p], s1, 4);
    float4 nb[8];
#pragma unroll
    for (int t = 0; t < 4; ++t)
#pragma unroll
        for (int p = 0; p < 2; ++p)
            nb[t*2+p] = selred(na[t*2+p], na[(t+4)*2+p], s2, 8);
    float4 nc[4];
#pragma unroll
    for (int t = 0; t < 2; ++t)
#pragma unroll
        for (int p = 0; p < 2; ++p)
            nc[t*2+p] = selred(nb[t*2+p], nb[(t+2)*2+p], s3, 16);
    float4 nd[2];
#pragma unroll
    for (int p = 0; p < 2; ++p)
        nd[p] = selred(nc[p], nc[2+p], s4, 32);

    const int tt = s1 * 8 + s2 * 4 + s3 * 2 + s4;   // token owned by this lane
    {
        float4* pp = (float4*)&part[half][tg * 16 + tt][eg * 8];
        pp[0] = nd[0]; pp[1] = nd[1];
    }
    __syncthreads();

    // ---- top-4 + softmax, one lane per token ----
    float* scorebuf = xt;                     // reuse staging LDS
    if (tid < TPB) {
        float lg[NE];
#pragma unroll
        for (int e = 0; e < NE; ++e)
            lg[e] = part[0][tid][e] + part[1][tid][e] + bias[e];

        float vals[TOPK]; int idxs[TOPK]; unsigned chosen = 0u;
#pragma unroll
        for (int k = 0; k < TOPK; ++k) {
            float m = -INFINITY; int mi = 0;
#pragma unroll
            for (int e = 0; e < NE; ++e) {
                const bool take = (((chosen >> e) & 1u) == 0u) && (lg[e] > m);
                m  = take ? lg[e] : m;
                mi = take ? e : mi;
            }
            vals[k] = m; idxs[k] = mi; chosen |= (1u << (unsigned)mi);
        }
        const float mx = vals[0];
        float p[TOPK]; float sum = 0.f;
#pragma unroll
        for (int k = 0; k < TOPK; ++k) { p[k] = __expf(vals[k] - mx); sum += p[k]; }
        const float inv = 1.0f / sum;
#pragma unroll
        for (int e = 0; e < NE; ++e) {
            float v = 0.f;
#pragma unroll
            for (int k = 0; k < TOPK; ++k) v = (e == idxs[k]) ? p[k] * inv : v;
            scorebuf[tid * 33 + e] = v;       // stride 33: conflict-free stash
        }
        const int t = blockIdx.x * TPB + tid;
        float4 iv = make_float4((float)idxs[0], (float)idxs[1], (float)idxs[2], (float)idxs[3]);
        *reinterpret_cast<float4*>(out_idx + (size_t)t * TOPK) = iv;
    }
    __syncthreads();

    // coalesced score store: 2048 floats, 512 threads x float4
    {
        const int f = tid * 4;
        const int t = f >> 5, e = f & 31;
        float4 v = make_float4(scorebuf[t * 33 + e], scorebuf[t * 33 + e + 1],
                               scorebuf[t * 33 + e + 2], scorebuf[t * 33 + e + 3]);
        *reinterpret_cast<float4*>(out_scores + (size_t)blockIdx.x * TPB * NE + f) = v;
    }
}

extern "C" void kernel_launch(void* const* d_in, const int* in_sizes, int n_in,
                              void* d_out, int out_size, void* d_ws, size_t ws_size,
                              hipStream_t stream)
{
    const float* x = (const float*)d_in[0];
    const float* w = (const float*)d_in[1];
    const float* b = (const float*)d_in[2];
    const int T = in_sizes[0] / HIDDEN;            // 16384 tokens

    float* wt = (float*)d_ws;                      // [2880][32] = 368.6 KB scratch
    float* out        = (float*)d_out;
    float* out_scores = out;                       // [T, 32]
    float* out_idx    = out + (size_t)T * NE;      // [T, 4] as fp32 values

    transpose_w_kernel<<<dim3((NE * HIDDEN + 255) / 256), dim3(256), 0, stream>>>(w, wt);
    router_kernel<<<dim3(T / TPB), dim3(512), 0, stream>>>(x, wt, b, out_scores, out_idx);
}